// Round 11
// baseline (81.715 us; speedup 1.0000x reference)
//
#include <hip/hip_runtime.h>

#define NT 64
#define NBMAX 4096   // max 64-node buckets for LDS-hist binning
#define CAPB 2048    // fixed payload slots per bucket (mean ~1279 here)

typedef short bf16x8 __attribute__((ext_vector_type(8)));
typedef float f32x4  __attribute__((ext_vector_type(4)));

__device__ __forceinline__ unsigned short f2bf(float f) {
    unsigned u = __builtin_bit_cast(unsigned, f);
    unsigned r = (u + 0x7fffu + ((u >> 16) & 1u)) >> 16;   // round-nearest-even
    return (unsigned short)r;
}
__device__ __forceinline__ float bf2f(unsigned short h) {
    return __builtin_bit_cast(float, (unsigned)h << 16);
}
__device__ __forceinline__ unsigned pack2(float a, float b) {
    return (unsigned)f2bf(a) | ((unsigned)f2bf(b) << 16);
}

// ---------------------------------------------------------------------------
// Prep: W (4x64x64 f32) + root_w -> bf16, transposed [m][col][k], XOR-swizzled
// (byte ^= (col&7)<<4 within each 128B row). Also zeros cursor[0..nb]
// (cursor[nb] doubles as spill_cnt).
// ---------------------------------------------------------------------------
__global__ __launch_bounds__(256) void prep_w_kernel(
    const float* __restrict__ weight, const float* __restrict__ root_w,
    unsigned short* __restrict__ wt, int* __restrict__ cursor, int nb)
{
    int g = blockIdx.x * 256 + threadIdx.x;
    if (g <= nb) cursor[g] = 0;
    if (g >= 5 * 4096) return;
    int m = g >> 12, rem = g & 4095, c = rem >> 6, k = rem & 63;
    float v = (m < 4) ? weight[m * 4096 + k * 64 + c] : root_w[k * 64 + c];
    int byte = m * 8192 + c * 128 + ((k * 2) ^ ((c & 7) << 4));
    wt[byte >> 1] = f2bf(v);
}

// ---------------------------------------------------------------------------
// Fill: bin edges into fixed-capacity bucket slots. Per-block LDS hist ->
// one cursor atomic per (block,bucket) -> ranked writes. 512 blocks.
// payload = src | (dst&63)<<ssh | type<<tsh.  spill_cnt = &cursor[nb].
// ---------------------------------------------------------------------------
__global__ __launch_bounds__(256) void fillb_kernel(
    const int* __restrict__ ei, const int* __restrict__ et,
    int* __restrict__ cursor, int* __restrict__ spill,
    unsigned* __restrict__ payload,
    int n_edges, int nb, int ssh, int tsh)
{
    __shared__ int lh[NBMAX];
    __shared__ int lbase[NBMAX];
    const int chunk = (n_edges + gridDim.x - 1) / gridDim.x;
    const int lo = blockIdx.x * chunk;
    const int hi = min(lo + chunk, n_edges);
    for (int i = threadIdx.x; i < nb; i += 256) lh[i] = 0;
    __syncthreads();
    for (int e = lo + threadIdx.x; e < hi; e += 256)
        atomicAdd(&lh[ei[n_edges + e] >> 6], 1);
    __syncthreads();
    for (int i = threadIdx.x; i < nb; i += 256) {
        int c = lh[i];
        lbase[i] = c ? atomicAdd(&cursor[i], c) : 0;
        lh[i] = 0;
    }
    __syncthreads();
    for (int e = lo + threadIdx.x; e < hi; e += 256) {
        int src = ei[e];
        int d   = ei[n_edges + e];
        int t   = et[e];
        int b   = d >> 6;
        int r   = atomicAdd(&lh[b], 1);
        int pos = lbase[b] + r;
        if (pos < CAPB) {
            payload[(size_t)b * CAPB + pos] =
                (unsigned)src | ((unsigned)(d & 63) << ssh) | ((unsigned)t << tsh);
        } else {
            int sp = atomicAdd(&cursor[nb], 1);
            spill[sp] = e;
        }
    }
}

// ---------------------------------------------------------------------------
// MFMA GEMM v2 (operand-swapped): D = mfma(Wt_frag, x_frag) so each lane owns
// ONE node (lane&15) and 4 CONSECUTIVE cols per tile -> packed vector stores.
//   m in [0,3] -> y[m] = x @ weight[m]   (bf16, 8B stores)
//   m == 4     -> out  = x @ root_w + b  (f32, float4 stores)
// LDS: [0,8KB) x tile bf16 swizzled; [8KB,48KB) Wt (5 mats, pre-swizzled).
// ---------------------------------------------------------------------------
__global__ __launch_bounds__(256) void gemm_mfma2_kernel(
    const float* __restrict__ x, const uint4* __restrict__ wt4,
    const float* __restrict__ root_b,
    float* __restrict__ out, unsigned short* __restrict__ y, int n_nodes)
{
    __shared__ uint4 lds4[3072];   // 48 KB

    const int tid   = threadIdx.x;
    const int node0 = blockIdx.x * 64;

    // Stage all 5 Wt (pre-swizzled in global -> linear copy).
    for (int i = tid; i < 2560; i += 256) lds4[512 + i] = wt4[i];

    // Stage x tile: thread -> node n = tid>>2, k-chunk kq = tid&3 (16 elems).
    {
        int n    = tid >> 2;
        int kq   = tid & 3;
        int node = node0 + n;
        uint4 p0, p1;
        if (node < n_nodes) {
            const float4* src = reinterpret_cast<const float4*>(x)
                                + (size_t)node * 16 + kq * 4;
            float4 f0 = src[0], f1 = src[1], f2 = src[2], f3 = src[3];
            p0.x = pack2(f0.x, f0.y); p0.y = pack2(f0.z, f0.w);
            p0.z = pack2(f1.x, f1.y); p0.w = pack2(f1.z, f1.w);
            p1.x = pack2(f2.x, f2.y); p1.y = pack2(f2.z, f2.w);
            p1.z = pack2(f3.x, f3.y); p1.w = pack2(f3.z, f3.w);
        } else {
            p0 = make_uint4(0, 0, 0, 0);
            p1 = p0;
        }
        int s0 = (kq * 2) ^ (n & 7);
        lds4[n * 8 + s0]       = p0;
        lds4[n * 8 + (s0 ^ 1)] = p1;
    }
    __syncthreads();

    const int wv = tid >> 6;
    const int l  = tid & 63;
    const int lo = l & 15;
    const int hi = l >> 4;

    // B-operand (x): lane&15 = node-within-tile. Same reads as before.
    const int arow = wv * 16 + lo;
    bf16x8 xb0 = *reinterpret_cast<const bf16x8*>(
        &lds4[arow * 8 + ((0 + hi) ^ (arow & 7))]);
    bf16x8 xb1 = *reinterpret_cast<const bf16x8*>(
        &lds4[arow * 8 + ((4 + hi) ^ (arow & 7))]);

    const int node   = node0 + wv * 16 + lo;   // this lane's output node
    const bool valid = (node < n_nodes);

    for (int m = 0; m < 5; ++m) {
        f32x4 acc[4];
        #pragma unroll
        for (int j = 0; j < 4; ++j)
            acc[j] = (f32x4){0.f, 0.f, 0.f, 0.f};

        #pragma unroll
        for (int j = 0; j < 4; ++j) {
            int c     = j * 16 + lo;            // A-operand row = W col
            int bbase = 512 + m * 512 + c * 8;
            bf16x8 w0 = *reinterpret_cast<const bf16x8*>(
                &lds4[bbase + ((0 + hi) ^ (c & 7))]);
            acc[j] = __builtin_amdgcn_mfma_f32_16x16x32_bf16(w0, xb0, acc[j], 0, 0, 0);
            bf16x8 w1 = *reinterpret_cast<const bf16x8*>(
                &lds4[bbase + ((4 + hi) ^ (c & 7))]);
            acc[j] = __builtin_amdgcn_mfma_f32_16x16x32_bf16(w1, xb1, acc[j], 0, 0, 0);
        }

        // D layout: lane holds node (fixed) x cols {j*16 + hi*4 + r}.
        if (m < 4) {
            if (valid) {
                unsigned short* __restrict__ ym = y + (size_t)m * n_nodes * 64;
                #pragma unroll
                for (int j = 0; j < 4; ++j) {
                    uint2 o;
                    o.x = pack2(acc[j][0], acc[j][1]);
                    o.y = pack2(acc[j][2], acc[j][3]);
                    *reinterpret_cast<uint2*>(
                        &ym[(size_t)node * 64 + j * 16 + hi * 4]) = o;
                }
            }
        } else {
            if (valid) {
                #pragma unroll
                for (int j = 0; j < 4; ++j) {
                    float4 rb = reinterpret_cast<const float4*>(root_b)[j * 4 + hi];
                    float4 o  = make_float4(acc[j][0] + rb.x, acc[j][1] + rb.y,
                                            acc[j][2] + rb.z, acc[j][3] + rb.w);
                    *reinterpret_cast<float4*>(
                        &out[(size_t)node * 64 + j * 16 + hi * 4]) = o;
                }
            }
        }
    }
}

// ---------------------------------------------------------------------------
// Gather (bf16 y): one 1024-thread block per bucket; in-LDS counting sort by
// local dst, then 64 groups x 16 threads accumulate in registers (unroll x2).
// Also drains the (normally empty) spill list.
// ---------------------------------------------------------------------------
__global__ __launch_bounds__(1024) void gatherb3_kernel(
    const int* __restrict__ cursor, const unsigned* __restrict__ payload,
    const int* __restrict__ spill, const int* __restrict__ ei,
    const int* __restrict__ et,
    const unsigned short* __restrict__ y, float* __restrict__ out,
    int n_nodes, int n_edges, int nb, int ssh, int tsh)
{
    __shared__ unsigned raw[CAPB];
    __shared__ unsigned srt[CAPB];
    __shared__ int hist[64];
    __shared__ int hoff[65];

    const int tid = threadIdx.x;
    const int b   = blockIdx.x;
    const int n_in = min(cursor[b], CAPB);
    const unsigned* __restrict__ pl_base = payload + (size_t)b * CAPB;

    if (tid < 64) hist[tid] = 0;
    __syncthreads();
    for (int i = tid; i < n_in; i += 1024) {
        unsigned pl = pl_base[i];
        raw[i] = pl;
        atomicAdd(&hist[(pl >> ssh) & 63], 1);
    }
    __syncthreads();
    if (tid < 64) {                       // wave-parallel exclusive scan
        int v = hist[tid];
        int s = v;
        #pragma unroll
        for (int d = 1; d < 64; d <<= 1) {
            int u = __shfl_up(s, d, 64);
            if (tid >= d) s += u;
        }
        hoff[tid] = s - v;
        if (tid == 63) hoff[64] = s;
        hist[tid] = 0;
    }
    __syncthreads();
    for (int i = tid; i < n_in; i += 1024) {
        unsigned pl = raw[i];
        int lnode = (pl >> ssh) & 63;
        int r = atomicAdd(&hist[lnode], 1);
        srt[hoff[lnode] + r] = pl;
    }
    __syncthreads();

    const int g    = tid >> 4;
    const int cq   = tid & 15;
    const int node = b * 64 + g;
    const unsigned smask = (1u << ssh) - 1;
    const ushort4* __restrict__ y4 = reinterpret_cast<const ushort4*>(y);

    float4 acc = make_float4(0.f, 0.f, 0.f, 0.f);
    const int s0 = hoff[g];
    const int s1 = hoff[g + 1];
    int p = s0;
    for (; p + 1 < s1; p += 2) {          // unroll x2: paired independent loads
        unsigned pl0 = srt[p];
        unsigned pl1 = srt[p + 1];
        ushort4 v0 = y4[((long)(pl0 >> tsh) * n_nodes + (pl0 & smask)) * 16 + cq];
        ushort4 v1 = y4[((long)(pl1 >> tsh) * n_nodes + (pl1 & smask)) * 16 + cq];
        acc.x += bf2f(v0.x) + bf2f(v1.x);
        acc.y += bf2f(v0.y) + bf2f(v1.y);
        acc.z += bf2f(v0.z) + bf2f(v1.z);
        acc.w += bf2f(v0.w) + bf2f(v1.w);
    }
    if (p < s1) {
        unsigned pl = srt[p];
        ushort4 v = y4[((long)(pl >> tsh) * n_nodes + (pl & smask)) * 16 + cq];
        acc.x += bf2f(v.x); acc.y += bf2f(v.y);
        acc.z += bf2f(v.z); acc.w += bf2f(v.w);
    }

    // Spill drain (normally S == 0).
    const int S = cursor[nb];
    for (int i = 0; i < S; ++i) {
        int e = spill[i];
        int d = ei[n_edges + e];
        if ((d >> 6) == b && (d & 63) == g) {
            int src = ei[e];
            int t   = et[e];
            ushort4 v = y4[((long)t * n_nodes + src) * 16 + cq];
            acc.x += bf2f(v.x); acc.y += bf2f(v.y);
            acc.z += bf2f(v.z); acc.w += bf2f(v.w);
        }
    }

    if (node < n_nodes) {
        float4* o  = reinterpret_cast<float4*>(out) + (long)node * 16 + cq;
        float4 cur = *o;
        cur.x += acc.x; cur.y += acc.y; cur.z += acc.z; cur.w += acc.w;
        *o = cur;
    }
}

// --------------------- fallbacks (small workspace) -------------------------
__global__ __launch_bounds__(256) void gemm_fused2_kernel(
    const float* __restrict__ x, const float* __restrict__ weight,
    const float* __restrict__ root_w, const float* __restrict__ root_b,
    float* __restrict__ out, unsigned short* __restrict__ y, int n_nodes)
{
    __shared__ unsigned short xsT[64][72];
    __shared__ float ws[64][72];
    const int tid   = threadIdx.x;
    const int node0 = blockIdx.x * 64;
    #pragma unroll
    for (int i = 0; i < 4; ++i) {
        int v    = tid + i * 256;
        int r    = v >> 4;
        int cq   = v & 15;
        int node = node0 + r;
        float4 x4 = (node < n_nodes)
                        ? reinterpret_cast<const float4*>(x)[(size_t)node * 16 + cq]
                        : make_float4(0.f, 0.f, 0.f, 0.f);
        xsT[cq * 4 + 0][r] = f2bf(x4.x);
        xsT[cq * 4 + 1][r] = f2bf(x4.y);
        xsT[cq * 4 + 2][r] = f2bf(x4.z);
        xsT[cq * 4 + 3][r] = f2bf(x4.w);
    }
    const int ng = tid & 31;
    const int cg = tid >> 5;
    float bias[8];
    #pragma unroll
    for (int j = 0; j < 8; ++j) bias[j] = root_b[cg * 8 + j];
    for (int m = 0; m < 5; ++m) {
        const float* __restrict__ W = (m < 4) ? (weight + m * 4096) : root_w;
        __syncthreads();
        #pragma unroll
        for (int i = 0; i < 4; ++i) {
            int v  = tid + i * 256;
            int r  = v >> 4;
            int cq = v & 15;
            float4 w4 = reinterpret_cast<const float4*>(W)[v];
            ws[r][cq * 4 + 0] = w4.x; ws[r][cq * 4 + 1] = w4.y;
            ws[r][cq * 4 + 2] = w4.z; ws[r][cq * 4 + 3] = w4.w;
        }
        __syncthreads();
        float acc[2][8];
        #pragma unroll
        for (int i = 0; i < 2; ++i)
            #pragma unroll
            for (int j = 0; j < 8; ++j) acc[i][j] = 0.f;
        #pragma unroll 4
        for (int k = 0; k < 64; ++k) {
            unsigned xu = *reinterpret_cast<const unsigned*>(&xsT[k][ng * 2]);
            float xv0 = __builtin_bit_cast(float, xu << 16);
            float xv1 = __builtin_bit_cast(float, xu & 0xffff0000u);
            float4 wa = *reinterpret_cast<const float4*>(&ws[k][cg * 8]);
            float4 wb = *reinterpret_cast<const float4*>(&ws[k][cg * 8 + 4]);
            float wv[8] = {wa.x, wa.y, wa.z, wa.w, wb.x, wb.y, wb.z, wb.w};
            #pragma unroll
            for (int j = 0; j < 8; ++j) {
                acc[0][j] += xv0 * wv[j];
                acc[1][j] += xv1 * wv[j];
            }
        }
        #pragma unroll
        for (int i = 0; i < 2; ++i) {
            int node = node0 + ng * 2 + i;
            if (node >= n_nodes) continue;
            if (m < 4) {
                uint4 o;
                o.x = pack2(acc[i][0], acc[i][1]);
                o.y = pack2(acc[i][2], acc[i][3]);
                o.z = pack2(acc[i][4], acc[i][5]);
                o.w = pack2(acc[i][6], acc[i][7]);
                *reinterpret_cast<uint4*>(
                    &y[((size_t)m * n_nodes + node) * 64 + cg * 8]) = o;
            } else {
                float4 oa = make_float4(acc[i][0] + bias[0], acc[i][1] + bias[1],
                                        acc[i][2] + bias[2], acc[i][3] + bias[3]);
                float4 ob = make_float4(acc[i][4] + bias[4], acc[i][5] + bias[5],
                                        acc[i][6] + bias[6], acc[i][7] + bias[7]);
                reinterpret_cast<float4*>(&out[(size_t)node * 64 + cg * 8])[0] = oa;
                reinterpret_cast<float4*>(&out[(size_t)node * 64 + cg * 8])[1] = ob;
            }
        }
    }
}

__global__ __launch_bounds__(256) void scatter_kernel(
    const int* __restrict__ ei, const int* __restrict__ et,
    const unsigned short* __restrict__ y, float* __restrict__ out,
    int n_edges, int n_nodes)
{
    long idx = (long)blockIdx.x * blockDim.x + threadIdx.x;
    if (idx >= (long)n_edges * 16) return;
    int e  = (int)(idx >> 4);
    int cq = (int)(idx & 15);
    int src  = ei[e];
    int dstn = ei[n_edges + e];
    int t    = et[e];
    ushort4 v = reinterpret_cast<const ushort4*>(y)[((long)t * n_nodes + src) * 16 + cq];
    float* o = out + (long)dstn * 64 + cq * 4;
    atomicAdd(o + 0, bf2f(v.x));
    atomicAdd(o + 1, bf2f(v.y));
    atomicAdd(o + 2, bf2f(v.z));
    atomicAdd(o + 3, bf2f(v.w));
}

__global__ __launch_bounds__(256) void gemm_root_kernel(
    const float* __restrict__ x, const float* __restrict__ root_w,
    const float* __restrict__ root_b, float* __restrict__ out, int n_nodes)
{
    __shared__ float xs[NT][65];
    __shared__ float ws[64][65];
    const int tid   = threadIdx.x;
    const int node0 = blockIdx.x * NT;
    #pragma unroll
    for (int i = 0; i < 4; ++i) {
        int v  = tid + i * 256;
        int r  = v >> 4;
        int cq = v & 15;
        float4 w4 = reinterpret_cast<const float4*>(root_w)[v];
        ws[r][cq * 4 + 0] = w4.x; ws[r][cq * 4 + 1] = w4.y;
        ws[r][cq * 4 + 2] = w4.z; ws[r][cq * 4 + 3] = w4.w;
        int node = node0 + r;
        float4 x4 = (node < n_nodes)
                        ? reinterpret_cast<const float4*>(x)[node * 16 + cq]
                        : make_float4(0.f, 0.f, 0.f, 0.f);
        xs[r][cq * 4 + 0] = x4.x; xs[r][cq * 4 + 1] = x4.y;
        xs[r][cq * 4 + 2] = x4.z; xs[r][cq * 4 + 3] = x4.w;
    }
    __syncthreads();
    const int tc = (tid & 15) * 4;
    const int tr = (tid >> 4) * 4;
    float acc[4][4];
    #pragma unroll
    for (int i = 0; i < 4; ++i)
        #pragma unroll
        for (int j = 0; j < 4; ++j) acc[i][j] = 0.f;
    #pragma unroll 4
    for (int k = 0; k < 64; ++k) {
        float xv[4], wv[4];
        #pragma unroll
        for (int i = 0; i < 4; ++i) xv[i] = xs[tr + i][k];
        #pragma unroll
        for (int j = 0; j < 4; ++j) wv[j] = ws[k][tc + j];
        #pragma unroll
        for (int i = 0; i < 4; ++i)
            #pragma unroll
            for (int j = 0; j < 4; ++j) acc[i][j] += xv[i] * wv[j];
    }
    #pragma unroll
    for (int i = 0; i < 4; ++i) {
        int node = node0 + tr + i;
        if (node < n_nodes) {
            float4 o = make_float4(acc[i][0] + root_b[tc + 0], acc[i][1] + root_b[tc + 1],
                                   acc[i][2] + root_b[tc + 2], acc[i][3] + root_b[tc + 3]);
            reinterpret_cast<float4*>(out)[node * 16 + (tc >> 2)] = o;
        }
    }
}

__global__ __launch_bounds__(256) void edge_direct_kernel(
    const float* __restrict__ x, const int* __restrict__ ei,
    const int* __restrict__ et, const float* __restrict__ weight,
    float* __restrict__ out, int n_edges)
{
    int gwave  = (int)((blockIdx.x * (long)blockDim.x + threadIdx.x) >> 6);
    int lane   = threadIdx.x & 63;
    int nwaves = (int)(((long)gridDim.x * blockDim.x) >> 6);
    for (int e = gwave; e < n_edges; e += nwaves) {
        int src  = ei[e];
        int dstn = ei[n_edges + e];
        int t    = et[e];
        float xv = x[src * 64 + lane];
        const float* __restrict__ W = weight + t * 4096;
        float acc = 0.f;
        #pragma unroll 8
        for (int k = 0; k < 64; ++k) {
            float xk = __shfl(xv, k);
            acc += xk * W[k * 64 + lane];
        }
        atomicAdd(&out[(long)dstn * 64 + lane], acc);
    }
}

extern "C" void kernel_launch(void* const* d_in, const int* in_sizes, int n_in,
                              void* d_out, int out_size, void* d_ws, size_t ws_size,
                              hipStream_t stream) {
    const float* x      = (const float*)d_in[0];
    const int*   ei     = (const int*)d_in[1];   // [2, E] int32
    const int*   et     = (const int*)d_in[2];   // [E]
    const float* weight = (const float*)d_in[3]; // [4, 64, 64]
    const float* root_w = (const float*)d_in[4]; // [64, 64]
    const float* root_b = (const float*)d_in[5]; // [64]
    float* out = (float*)d_out;

    const int n_nodes = in_sizes[0] / 64;
    const int n_edges = in_sizes[2];
    const int nb      = (n_nodes + 63) >> 6;

    int ssh = 1;
    while ((1 << ssh) < n_nodes) ++ssh;   // bits for src
    const int tsh = ssh + 6;              // 6 bits for local dst

    const size_t wt_bytes = 5 * 4096 * sizeof(unsigned short);   // 40 KB
    const size_t y_bytes  = (size_t)4 * n_nodes * 64 * sizeof(unsigned short);
    const size_t b_bytes  = wt_bytes + y_bytes +
        ((size_t)nb + 1 + (size_t)nb * CAPB + n_edges) * 4;

    if (nb <= NBMAX && tsh + 2 <= 32 && ws_size >= b_bytes) {
        unsigned short* wt      = (unsigned short*)d_ws;
        unsigned short* y       = (unsigned short*)((char*)d_ws + wt_bytes);
        int*            cursor  = (int*)((char*)d_ws + wt_bytes + y_bytes); // nb+1
        unsigned*       payload = (unsigned*)(cursor + nb + 1);             // nb*CAPB
        int*            spill   = (int*)(payload + (size_t)nb * CAPB);      // n_edges

        prep_w_kernel<<<80, 256, 0, stream>>>(weight, root_w, wt, cursor, nb);
        fillb_kernel<<<512, 256, 0, stream>>>(ei, et, cursor, spill,
                                              payload, n_edges, nb, ssh, tsh);
        gemm_mfma2_kernel<<<nb, 256, 0, stream>>>(x, (const uint4*)wt, root_b,
                                                  out, y, n_nodes);
        gatherb3_kernel<<<nb, 1024, 0, stream>>>(
            cursor, payload, spill, ei, et, y, out,
            n_nodes, n_edges, nb, ssh, tsh);
    } else if (ws_size >= y_bytes) {
        unsigned short* y = (unsigned short*)d_ws;
        gemm_fused2_kernel<<<(n_nodes + 63) / 64, 256, 0, stream>>>(
            x, weight, root_w, root_b, out, y, n_nodes);
        long total  = (long)n_edges * 16;
        int  blocks = (int)((total + 255) / 256);
        scatter_kernel<<<blocks, 256, 0, stream>>>(ei, et, y, out, n_edges, n_nodes);
    } else {
        gemm_root_kernel<<<(n_nodes + NT - 1) / NT, 256, 0, stream>>>(
            x, root_w, root_b, out, n_nodes);
        edge_direct_kernel<<<4096, 256, 0, stream>>>(x, ei, et, weight, out, n_edges);
    }
}